// Round 12
// baseline (55.174 us; speedup 1.0000x reference)
//
#include <hip/hip_runtime.h>
#include <math.h>

typedef float        f32x2 __attribute__((ext_vector_type(2)));
typedef float        f32x4 __attribute__((ext_vector_type(4)));
typedef _Float16     f16x2 __attribute__((ext_vector_type(2)));
typedef _Float16     f16x8 __attribute__((ext_vector_type(8)));
typedef unsigned int u32;
typedef unsigned int u32x4 __attribute__((ext_vector_type(4)));

// Problem constants
#define HW_    4096
#define CH_STR 8192          // channel (or o) stride in x/out = D*HW
#define B_STR  262144        // batch stride = C*D*HW
#define NPIX   131072
#define NKSTEP 20            // 640 padded k-slots / 32
#define NSLICE 80            // 640 / 8
#define NBEL   (2*NKSTEP*2*64*8)   // frag elems: var*kstep*ohalf*lane*j = 40960

// Scales: u' = 1024*u, w' = 512*w  ->  acc = 2^19 * oc; atan2 is scale-invariant.
// Keeps fp16 split residuals in the fp16 NORMAL range (no subnormal flush).
#define WSCALE 512.0f
#define USCALE 1024.0f

// d_ws layout: frag _Float16[40960] at +0 (81,920 B); ce_tab u32[80] at +81920.

// ---------------------------------------------------------------------------
// Prep (validated R8/R10): k-enumeration = rows c padded to rlen8(c)=8*(c/8+1)
// slots (total 640). frag[var][ks][oh][lane][j] = fp16 RNE split (var=0 hi,
// var=1 residual) of 512*foldW at k = ks*32 + 8*(lane>>4) + j,
// o = oh*16 + (lane&15); fold: e<c -> W[o,c,e]+W[o,e,c]; e==c -> W[o,c,c];
// pad -> 0. ce_tab[s] = (c<<16)|e0 per 8-k slice s.
// ---------------------------------------------------------------------------
__global__ void prep(const float* __restrict__ w,
                     _Float16* __restrict__ bfr,
                     unsigned int* __restrict__ ct) {
    int idx = blockIdx.x * 256 + threadIdx.x;
    if (idx < NBEL) {
        int j    =  idx & 7;
        int lane = (idx >> 3) & 63;
        int oh   = (idx >> 9) & 1;
        int t    =  idx >> 10;
        int ks   = t % NKSTEP;
        int var  = t / NKSTEP;
        int k = ks * 32 + ((lane >> 4) << 3) + j;
        int c = 0, base = 0;
        for (; c < 32; ++c) { int rl = 8 * ((c >> 3) + 1); if (k < base + rl) break; base += rl; }
        int e = k - base;
        int o = oh * 16 + (lane & 15);
        float v = 0.0f;
        if (e <= c)
            v = (e == c) ? w[o * 1024 + c * 33]
                         : (w[o * 1024 + c * 32 + e] + w[o * 1024 + e * 32 + c]);
        v *= WSCALE;
        _Float16 h = (_Float16)v;                    // RNE hi
        if (var) h = (_Float16)(v - (float)h);       // RNE residual (lo)
        bfr[idx] = h;
    } else if (idx < NBEL + NSLICE) {
        int s = idx - NBEL, k = s * 8, c = 0, base = 0;
        for (; c < 32; ++c) { int rl = 8 * ((c >> 3) + 1); if (k < base + rl) break; base += rl; }
        ct[s] = ((unsigned int)c << 16) | (unsigned int)(k - base);
    }
}

// ---------------------------------------------------------------------------
// Main (structure/indices validated R8/R10; R11 = u32-pack fragments,
// pre-scaled c-side pair table + b64 read, unroll 4).
// Block = 256 thr = 4 waves, each wave owns 16 px. Wave tile 16px x 32o,
// K = 640 in 20 steps of 32. A built in registers (HW A layout; any HW
// k-permutation cancels: B uses the same (lane,j)->k map).
// acc = Ah*Bh + Ah*Bl + Al*Bh in fp32 MFMA accumulators.
// Trig row layout per px (stride 132 dwords = 528 B, 16B-aligned):
//   [0..63]   (1024*cos(c), 1024*sin(c)) interleaved pairs  -> b64 c-side
//   [64..95]  cos (unscaled, e-side)                        -> b128 x2
//   [96..127] sin (unscaled, e-side)                        -> b128 x2
// ---------------------------------------------------------------------------
#define TPB   256
#define TSTR  132   // trig row stride (dwords)

__device__ __forceinline__ f16x8 pack8(u32 a, u32 b, u32 c, u32 d) {
    u32x4 t = {a, b, c, d};
    return __builtin_bit_cast(f16x8, t);
}

__device__ __forceinline__ u32 pkrtz_u(float a, float b) {
    return __builtin_bit_cast(u32, __builtin_amdgcn_cvt_pkrtz(a, b));
}

#define LOAD_TRIG(ST, CS, CE0, CE1, SE0, SE1) do { \
    const int c_ = (int)((ST) >> 16), e_ = (int)((ST) & 0xffffu); \
    CS  = *(const f32x2*)(tp + 2 * c_); \
    CE0 = *(const f32x4*)(tp + 64 + e_); \
    CE1 = *(const f32x4*)(tp + 68 + e_); \
    SE0 = *(const f32x4*)(tp + 96 + e_); \
    SE1 = *(const f32x4*)(tp + 100 + e_); \
} while (0)

__global__ __launch_bounds__(TPB, 4) void mfma_bilinear(
    const float* __restrict__ x,
    const _Float16* __restrict__ bfr,
    const unsigned int* __restrict__ ct,
    const float* __restrict__ bias,
    float* __restrict__ out)
{
    __shared__ float trig[64 * TSTR];   // 33,792 B

    const int lane = threadIdx.x & 63;
    const int wv   = threadIdx.x >> 6;       // wave id 0..3
    const int lg   = lane >> 4;              // k-subgroup 0..3
    const int lidm = lane & 15;              // A-row / B-col within fragment
    const int P0   = blockIdx.x * 64;
    const int b    = P0 >> 13;
    const int d    = (P0 >> 12) & 1;
    const int hw0  = P0 & 4095;              // 64-aligned, block stays in (b,d)
    const int obase = b * B_STR + d * HW_ + hw0;   // + px + (c|o)*CH_STR

    const int px = wv * 16 + lidm;           // block-local pixel (my A-row)
    float* tp = trig + px * TSTR;

    // ---- trig prologue: 4 lanes (lg=0..3) cover the 32 channels of px ----
    #pragma unroll
    for (int m = 0; m < 8; ++m) {
        int c = lg * 8 + m;
        float xv = x[obase + px + c * CH_STR];
        float s, co; __sincosf(xv, &s, &co);
        *(f32x2*)(tp + 2 * c) = (f32x2){co * USCALE, s * USCALE};
        tp[64 + c] = co;
        tp[96 + c] = s;
    }
    // same-wave DS ordering makes the reads below safe without a barrier.

    f32x4 acc_r[2] = {{0.f,0.f,0.f,0.f}, {0.f,0.f,0.f,0.f}};
    f32x4 acc_i[2] = {{0.f,0.f,0.f,0.f}, {0.f,0.f,0.f,0.f}};

    const f16x8* __restrict__ bfv = (const f16x8*)bfr;  // 16B units

    // ---- pipeline prologue: state for ks=0 + slice word for ks=1 ----
    f16x8 bh0 = bfv[((0) * 2 + 0) * 64 + lane];
    f16x8 bh1 = bfv[((0) * 2 + 1) * 64 + lane];
    f16x8 bl0 = bfv[((NKSTEP) * 2 + 0) * 64 + lane];
    f16x8 bl1 = bfv[((NKSTEP) * 2 + 1) * 64 + lane];
    unsigned int st0 = ct[lg];
    f32x2 cs; f32x4 ce0, ce1, se0, se1;
    LOAD_TRIG(st0, cs, ce0, ce1, se0, se1);
    unsigned int stN = ct[4 + lg];           // slice word for ks=1

    #pragma unroll 4
    for (int ks = 0; ks < NKSTEP; ++ks) {
        const int kn  = (ks < NKSTEP - 1) ? ks + 1 : ks;
        const int knn = (kn < NKSTEP - 1) ? kn + 1 : kn;

        // ---- issue ALL next-iteration loads first (one k-step of slack) ----
        f16x8 nbh0 = bfv[(( 0 + kn) * 2 + 0) * 64 + lane];
        f16x8 nbh1 = bfv[(( 0 + kn) * 2 + 1) * 64 + lane];
        f16x8 nbl0 = bfv[((NKSTEP + kn) * 2 + 0) * 64 + lane];
        f16x8 nbl1 = bfv[((NKSTEP + kn) * 2 + 1) * 64 + lane];
        f32x2 ncs; f32x4 nce0, nce1, nse0, nse1;
        LOAD_TRIG(stN, ncs, nce0, nce1, nse0, nse1);
        unsigned int stNN = ct[knn * 4 + lg];

        // ---- compute current k-step (c-side already scaled by 1024) ----
        const float ccs = cs[0];
        const float scs = cs[1];

        u32 hr[4], hi[4], lr[4], li[4];
        #pragma unroll
        for (int p = 0; p < 4; ++p) {
            const float cea = (2*p     < 4) ? ce0[2*p]     : ce1[2*p - 4];
            const float sea = (2*p     < 4) ? se0[2*p]     : se1[2*p - 4];
            const float ceb = (2*p + 1 < 4) ? ce0[2*p + 1] : ce1[2*p - 3];
            const float seb = (2*p + 1 < 4) ? se0[2*p + 1] : se1[2*p - 3];
            const float ur0 = fmaf(ccs, cea, -(scs * sea));
            const float ui0 = fmaf(ccs, sea,   scs * cea);
            const float ur1 = fmaf(ccs, ceb, -(scs * seb));
            const float ui1 = fmaf(ccs, seb,   scs * ceb);
            hr[p] = pkrtz_u(ur0, ur1);                     // packed hi (RTZ)
            hi[p] = pkrtz_u(ui0, ui1);
            const f16x2 h2r = __builtin_bit_cast(f16x2, hr[p]);
            const f16x2 h2i = __builtin_bit_cast(f16x2, hi[p]);
            lr[p] = pkrtz_u(ur0 - (float)h2r[0], ur1 - (float)h2r[1]);  // exact residual
            li[p] = pkrtz_u(ui0 - (float)h2i[0], ui1 - (float)h2i[1]);
        }
        const f16x8 ahr = pack8(hr[0], hr[1], hr[2], hr[3]);
        const f16x8 ahi = pack8(hi[0], hi[1], hi[2], hi[3]);
        const f16x8 alr = pack8(lr[0], lr[1], lr[2], lr[3]);
        const f16x8 ali = pack8(li[0], li[1], li[2], li[3]);

        acc_r[0] = __builtin_amdgcn_mfma_f32_16x16x32_f16(ahr, bh0, acc_r[0], 0, 0, 0);
        acc_i[0] = __builtin_amdgcn_mfma_f32_16x16x32_f16(ahi, bh0, acc_i[0], 0, 0, 0);
        acc_r[1] = __builtin_amdgcn_mfma_f32_16x16x32_f16(ahr, bh1, acc_r[1], 0, 0, 0);
        acc_i[1] = __builtin_amdgcn_mfma_f32_16x16x32_f16(ahi, bh1, acc_i[1], 0, 0, 0);
        acc_r[0] = __builtin_amdgcn_mfma_f32_16x16x32_f16(ahr, bl0, acc_r[0], 0, 0, 0);
        acc_i[0] = __builtin_amdgcn_mfma_f32_16x16x32_f16(ahi, bl0, acc_i[0], 0, 0, 0);
        acc_r[1] = __builtin_amdgcn_mfma_f32_16x16x32_f16(ahr, bl1, acc_r[1], 0, 0, 0);
        acc_i[1] = __builtin_amdgcn_mfma_f32_16x16x32_f16(ahi, bl1, acc_i[1], 0, 0, 0);
        acc_r[0] = __builtin_amdgcn_mfma_f32_16x16x32_f16(alr, bh0, acc_r[0], 0, 0, 0);
        acc_i[0] = __builtin_amdgcn_mfma_f32_16x16x32_f16(ali, bh0, acc_i[0], 0, 0, 0);
        acc_r[1] = __builtin_amdgcn_mfma_f32_16x16x32_f16(alr, bh1, acc_r[1], 0, 0, 0);
        acc_i[1] = __builtin_amdgcn_mfma_f32_16x16x32_f16(ali, bh1, acc_i[1], 0, 0, 0);

        // ---- rotate pipeline state ----
        bh0 = nbh0; bh1 = nbh1; bl0 = nbl0; bl1 = nbl1;
        cs = ncs;
        ce0 = nce0; ce1 = nce1; se0 = nse0; se1 = nse1;
        stN = stNN;
    }

    // ---- epilogue: C/D (m89): col o = oh*16 + (lane&15), row px = 4*lg + q ----
    #pragma unroll
    for (int oh = 0; oh < 2; ++oh) {
        const int o = oh * 16 + lidm;
        const float bo = bias[o];
        #pragma unroll
        for (int q = 0; q < 4; ++q) {
            const int pxr = wv * 16 + lg * 4 + q;
            out[obase + pxr + o * CH_STR] = atan2f(acc_i[oh][q], acc_r[oh][q]) + bo;
        }
    }
}

// ---------------------------------------------------------------------------
extern "C" void kernel_launch(void* const* d_in, const int* in_sizes, int n_in,
                              void* d_out, int out_size, void* d_ws, size_t ws_size,
                              hipStream_t stream) {
    const float* x    = (const float*)d_in[0];
    const float* w    = (const float*)d_in[1];
    const float* bias = (const float*)d_in[2];
    float* out        = (float*)d_out;
    _Float16*     bfr = (_Float16*)d_ws;                          // 81,920 B
    unsigned int* ct  = (unsigned int*)((char*)d_ws + 81920);     // 320 B

    {
        int n = NBEL + NSLICE;
        prep<<<(n + 255) / 256, 256, 0, stream>>>(w, bfr, ct);
    }
    {
        int grid = NPIX / 64;   // 2048 blocks x 4 waves
        mfma_bilinear<<<grid, TPB, 0, stream>>>(x, bfr, ct, bias, out);
    }
}

// Round 13
// 53.577 us; speedup vs baseline: 1.0298x; 1.0298x over previous
//
#include <hip/hip_runtime.h>
#include <math.h>

typedef float        f32x2 __attribute__((ext_vector_type(2)));
typedef float        f32x4 __attribute__((ext_vector_type(4)));
typedef _Float16     f16x2 __attribute__((ext_vector_type(2)));
typedef _Float16     f16x8 __attribute__((ext_vector_type(8)));
typedef unsigned int u32;
typedef unsigned int u32x4 __attribute__((ext_vector_type(4)));

// Problem constants
#define HW_    4096
#define CH_STR 8192          // channel (or o) stride in x/out = D*HW
#define B_STR  262144        // batch stride = C*D*HW
#define NPIX   131072
#define NKSTEP 20            // 640 padded k-slots / 32
#define NSLICE 80            // 640 / 8
#define NCT    84            // ct padded (+1 step) so 2-deep prefetch stays in bounds
#define NBEL   (NKSTEP*2*2*64*8)   // 40960 frag elems

// Scales: u' = 1024*u, w' = 512*w  ->  acc = 2^19 * oc; atan2 is scale-invariant.
#define WSCALE 512.0f
#define USCALE 1024.0f

// d_ws layout: frag _Float16[40960] at +0 (81,920 B); ct u32[84] at +81920.

// ---------------------------------------------------------------------------
// Prep (fold validated R8-R11; R12 re-layouts only).
// NEW frag layout: [ks][frag=var*2+oh][lane][j]  -> per-step 4096 B block,
// fragment imm offsets 0/1024/2048/3072.  Content per element unchanged:
// fp16 RNE split (var=0 hi, var=1 residual) of 512*foldW at
// k = ks*32 + 8*(lane>>4) + j, o = oh*16 + (lane&15).
// ct[s] = (c*8)<<16 | (e0*4)  (ready LDS byte offsets), zero-padded to 84.
// ---------------------------------------------------------------------------
__global__ void prep(const float* __restrict__ w,
                     _Float16* __restrict__ bfr,
                     u32* __restrict__ ct) {
    int idx = blockIdx.x * 256 + threadIdx.x;
    if (idx < NBEL) {
        int j    =  idx & 7;
        int lane = (idx >> 3) & 63;
        int frag = (idx >> 9) & 3;      // var*2 + oh
        int ks   =  idx >> 11;
        int var  = frag >> 1;
        int oh   = frag & 1;
        int k = ks * 32 + ((lane >> 4) << 3) + j;
        int c = 0, base = 0;
        for (; c < 32; ++c) { int rl = 8 * ((c >> 3) + 1); if (k < base + rl) break; base += rl; }
        int e = k - base;
        int o = oh * 16 + (lane & 15);
        float v = 0.0f;
        if (e <= c)
            v = (e == c) ? w[o * 1024 + c * 33]
                         : (w[o * 1024 + c * 32 + e] + w[o * 1024 + e * 32 + c]);
        v *= WSCALE;
        _Float16 h = (_Float16)v;                    // RNE hi
        if (var) h = (_Float16)(v - (float)h);       // RNE residual (lo)
        bfr[idx] = h;
    } else if (idx < NBEL + NCT) {
        int s = idx - NBEL;
        u32 v = 0;
        if (s < NSLICE) {
            int k = s * 8, c = 0, base = 0;
            for (; c < 32; ++c) { int rl = 8 * ((c >> 3) + 1); if (k < base + rl) break; base += rl; }
            v = ((u32)(c * 8) << 16) | (u32)((k - base) * 4);
        }
        ct[s] = v;
    }
}

// ---------------------------------------------------------------------------
// Main (MFMA structure/indices validated R8-R11; R12 = streaming addresses:
// per-step-contiguous B blocks behind one advancing uniform pointer + imm
// offsets, no clamp ternaries (last step peeled), byte-offset ct words).
// Block = 256 thr = 4 waves, each wave owns 16 px. Wave tile 16px x 32o,
// K = 640 in 20 steps of 32. acc = Ah*Bh + Ah*Bl + Al*Bh (fp32 MFMA accs).
// Trig row per px (132 dwords = 528 B): [0..63] scaled (cos,sin) pairs,
// [64..95] cos, [96..127] sin (both unscaled e-side).
// ---------------------------------------------------------------------------
#define TPB   256
#define TSTR  132   // trig row stride (dwords)

__device__ __forceinline__ f16x8 pack8(u32 a, u32 b, u32 c, u32 d) {
    u32x4 t = {a, b, c, d};
    return __builtin_bit_cast(f16x8, t);
}
__device__ __forceinline__ u32 pkrtz_u(float a, float b) {
    return __builtin_bit_cast(u32, __builtin_amdgcn_cvt_pkrtz(a, b));
}

__global__ __launch_bounds__(TPB, 4) void mfma_bilinear(
    const float* __restrict__ x,
    const _Float16* __restrict__ bfr,
    const u32* __restrict__ ct,
    const float* __restrict__ bias,
    float* __restrict__ out)
{
    __shared__ float trig[64 * TSTR];   // 33,792 B

    const int lane = threadIdx.x & 63;
    const int wv   = threadIdx.x >> 6;       // wave id 0..3
    const int lg   = lane >> 4;              // k-subgroup 0..3
    const int lidm = lane & 15;              // A-row / B-col within fragment
    const int P0   = blockIdx.x * 64;
    const int b    = P0 >> 13;
    const int d    = (P0 >> 12) & 1;
    const int hw0  = P0 & 4095;              // 64-aligned, block stays in (b,d)
    const int obase = b * B_STR + d * HW_ + hw0;   // + px + (c|o)*CH_STR

    const int px = wv * 16 + lidm;           // block-local pixel (my A-row)
    float* tp = trig + px * TSTR;
    const char* tb = (const char*)tp;        // byte base of my trig row

    // ---- trig prologue: 4 lanes (lg=0..3) cover the 32 channels of px ----
    #pragma unroll
    for (int m = 0; m < 8; ++m) {
        int c = lg * 8 + m;
        float xv = x[obase + px + c * CH_STR];
        float s, co; __sincosf(xv, &s, &co);
        *(f32x2*)(tp + 2 * c) = (f32x2){co * USCALE, s * USCALE};
        tp[64 + c] = co;
        tp[96 + c] = s;
    }
    // same-wave DS ordering makes the reads below safe without a barrier.

    f32x4 acc_r[2] = {{0.f,0.f,0.f,0.f}, {0.f,0.f,0.f,0.f}};
    f32x4 acc_i[2] = {{0.f,0.f,0.f,0.f}, {0.f,0.f,0.f,0.f}};

    // Streaming pointers: uniform base + (lane/lg) voffset + imm offsets.
    const char* ubp = (const char*)bfr;      // step-ks B block at ubp (+= 4096)
    const char* uct = (const char*)ct;       // word(ks) at uct (+= 16)
    const int lo16 = lane * 16;
    const int lg4  = lg * 4;

#define LDB(OFF)      (*(const f16x8*)(ubp + lo16 + (OFF)))
#define LDCT(OFF)     (*(const u32*)(uct + lg4 + (OFF)))
#define LOAD_TRIG(ST, CS, CE0, CE1, SE0, SE1) do { \
    const u32 st_ = (ST); \
    const int cB = (int)(st_ >> 16), eB = (int)(st_ & 0xffffu); \
    CS  = *(const f32x2*)(tb + cB); \
    CE0 = *(const f32x4*)(tb + 256 + eB); \
    CE1 = *(const f32x4*)(tb + 272 + eB); \
    SE0 = *(const f32x4*)(tb + 384 + eB); \
    SE1 = *(const f32x4*)(tb + 400 + eB); \
} while (0)

// One k-step: u-gen + fp16 RTZ 2-split + 12 MFMA (validated structure).
#define COMPUTE_STEP(CS, CE0, CE1, SE0, SE1, BH0, BH1, BL0, BL1) do { \
    const float ccs = (CS)[0]; \
    const float scs = (CS)[1]; \
    u32 hr[4], hi[4], lr[4], li[4]; \
    _Pragma("unroll") \
    for (int p = 0; p < 4; ++p) { \
        const float cea = (2*p     < 4) ? (CE0)[2*p]     : (CE1)[2*p - 4]; \
        const float sea = (2*p     < 4) ? (SE0)[2*p]     : (SE1)[2*p - 4]; \
        const float ceb = (2*p + 1 < 4) ? (CE0)[2*p + 1] : (CE1)[2*p - 3]; \
        const float seb = (2*p + 1 < 4) ? (SE0)[2*p + 1] : (SE1)[2*p - 3]; \
        const float ur0 = fmaf(ccs, cea, -(scs * sea)); \
        const float ui0 = fmaf(ccs, sea,   scs * cea); \
        const float ur1 = fmaf(ccs, ceb, -(scs * seb)); \
        const float ui1 = fmaf(ccs, seb,   scs * ceb); \
        hr[p] = pkrtz_u(ur0, ur1); \
        hi[p] = pkrtz_u(ui0, ui1); \
        const f16x2 h2r = __builtin_bit_cast(f16x2, hr[p]); \
        const f16x2 h2i = __builtin_bit_cast(f16x2, hi[p]); \
        lr[p] = pkrtz_u(ur0 - (float)h2r[0], ur1 - (float)h2r[1]); \
        li[p] = pkrtz_u(ui0 - (float)h2i[0], ui1 - (float)h2i[1]); \
    } \
    const f16x8 ahr = pack8(hr[0], hr[1], hr[2], hr[3]); \
    const f16x8 ahi = pack8(hi[0], hi[1], hi[2], hi[3]); \
    const f16x8 alr = pack8(lr[0], lr[1], lr[2], lr[3]); \
    const f16x8 ali = pack8(li[0], li[1], li[2], li[3]); \
    acc_r[0] = __builtin_amdgcn_mfma_f32_16x16x32_f16(ahr, BH0, acc_r[0], 0, 0, 0); \
    acc_i[0] = __builtin_amdgcn_mfma_f32_16x16x32_f16(ahi, BH0, acc_i[0], 0, 0, 0); \
    acc_r[1] = __builtin_amdgcn_mfma_f32_16x16x32_f16(ahr, BH1, acc_r[1], 0, 0, 0); \
    acc_i[1] = __builtin_amdgcn_mfma_f32_16x16x32_f16(ahi, BH1, acc_i[1], 0, 0, 0); \
    acc_r[0] = __builtin_amdgcn_mfma_f32_16x16x32_f16(ahr, BL0, acc_r[0], 0, 0, 0); \
    acc_i[0] = __builtin_amdgcn_mfma_f32_16x16x32_f16(ahi, BL0, acc_i[0], 0, 0, 0); \
    acc_r[1] = __builtin_amdgcn_mfma_f32_16x16x32_f16(ahr, BL1, acc_r[1], 0, 0, 0); \
    acc_i[1] = __builtin_amdgcn_mfma_f32_16x16x32_f16(ahi, BL1, acc_i[1], 0, 0, 0); \
    acc_r[0] = __builtin_amdgcn_mfma_f32_16x16x32_f16(alr, BH0, acc_r[0], 0, 0, 0); \
    acc_i[0] = __builtin_amdgcn_mfma_f32_16x16x32_f16(ali, BH0, acc_i[0], 0, 0, 0); \
    acc_r[1] = __builtin_amdgcn_mfma_f32_16x16x32_f16(alr, BH1, acc_r[1], 0, 0, 0); \
    acc_i[1] = __builtin_amdgcn_mfma_f32_16x16x32_f16(ali, BH1, acc_i[1], 0, 0, 0); \
} while (0)

    // ---- pipeline prologue: step-0 state + slice word for step 1 ----
    f16x8 bh0 = LDB(0), bh1 = LDB(1024), bl0 = LDB(2048), bl1 = LDB(3072);
    f32x2 cs; f32x4 ce0, ce1, se0, se1;
    LOAD_TRIG(LDCT(0), cs, ce0, ce1, se0, se1);
    u32 stN = LDCT(16);
    ubp += 4096;                         // -> step 1 block

    #pragma unroll 4
    for (int ks = 0; ks < NKSTEP - 1; ++ks) {
        // prefetch step ks+1 (B block at ubp; trig via stN; word for ks+2)
        f16x8 nbh0 = LDB(0), nbh1 = LDB(1024), nbl0 = LDB(2048), nbl1 = LDB(3072);
        f32x2 ncs; f32x4 nce0, nce1, nse0, nse1;
        LOAD_TRIG(stN, ncs, nce0, nce1, nse0, nse1);
        u32 stN2 = LDCT(32);             // word(ks+2); padded table keeps it in-bounds

        COMPUTE_STEP(cs, ce0, ce1, se0, se1, bh0, bh1, bl0, bl1);

        bh0 = nbh0; bh1 = nbh1; bl0 = nbl0; bl1 = nbl1;
        cs = ncs; ce0 = nce0; ce1 = nce1; se0 = nse0; se1 = nse1;
        stN = stN2;
        ubp += 4096; uct += 16;
    }
    // peeled final step (no prefetch, no clamps anywhere)
    COMPUTE_STEP(cs, ce0, ce1, se0, se1, bh0, bh1, bl0, bl1);

    // ---- epilogue: C/D (m89): col o = oh*16 + (lane&15), row px = 4*lg + q ----
    #pragma unroll
    for (int oh = 0; oh < 2; ++oh) {
        const int o = oh * 16 + lidm;
        const float bo = bias[o];
        #pragma unroll
        for (int q = 0; q < 4; ++q) {
            const int pxr = wv * 16 + lg * 4 + q;
            out[obase + pxr + o * CH_STR] = atan2f(acc_i[oh][q], acc_r[oh][q]) + bo;
        }
    }
#undef LDB
#undef LDCT
#undef LOAD_TRIG
#undef COMPUTE_STEP
}

// ---------------------------------------------------------------------------
extern "C" void kernel_launch(void* const* d_in, const int* in_sizes, int n_in,
                              void* d_out, int out_size, void* d_ws, size_t ws_size,
                              hipStream_t stream) {
    const float* x    = (const float*)d_in[0];
    const float* w    = (const float*)d_in[1];
    const float* bias = (const float*)d_in[2];
    float* out        = (float*)d_out;
    _Float16* bfr = (_Float16*)d_ws;                  // 81,920 B
    u32*      ct  = (u32*)((char*)d_ws + 81920);      // 336 B

    {
        int n = NBEL + NCT;
        prep<<<(n + 255) / 256, 256, 0, stream>>>(w, bfr, ct);
    }
    {
        int grid = NPIX / 64;   // 2048 blocks x 4 waves
        mfma_bilinear<<<grid, TPB, 0, stream>>>(x, bfr, ct, bias, out);
    }
}